// Round 13
// baseline (774.860 us; speedup 1.0000x reference)
//
#include <hip/hip_runtime.h>

// Problem constants
constexpr int Bz = 512;   // batch
constexpr int Tz = 256;   // seq len
constexpr int Hz = 256;   // hidden
constexpr int Pz = 14;    // predict dim
constexpr int GB = 32;    // batch groups
constexpr int GS = 8;     // hidden slices per group
constexpr int BT = 16;    // batch per group (512/32)
constexpr int KP = 264;   // LDS h row stride (shorts)
constexpr int XS = 260;   // x LDS row stride (floats)

typedef short s8v __attribute__((ext_vector_type(8)));
typedef float f4v __attribute__((ext_vector_type(4)));
typedef unsigned long long u64;

__device__ __forceinline__ short f2bf(float f) {
  unsigned u = __float_as_uint(f);
  u = (u + 0x7fffu + ((u >> 16) & 1u)) >> 16;   // RNE
  return (short)u;
}
__device__ __forceinline__ float bf2f(short s) {
  return __uint_as_float(((unsigned)(unsigned short)s) << 16);
}
// Fast gates (R11/R14-proven numerics: identical absmax to libm path)
__device__ __forceinline__ float sigm(float v) {
  return __builtin_amdgcn_rcpf(1.0f + __builtin_amdgcn_exp2f(-1.442695041f * v));
}
__device__ __forceinline__ float tanh_f(float v) {
  return 1.0f - 2.0f * __builtin_amdgcn_rcpf(__builtin_amdgcn_exp2f(2.885390082f * v) + 1.0f);
}

__device__ __forceinline__ u64 llc_load64(const u64* p) {
  return __hip_atomic_load(p, __ATOMIC_RELAXED, __HIP_MEMORY_SCOPE_AGENT);
}
__device__ __forceinline__ unsigned llc_load32(const unsigned* p) {
  return __hip_atomic_load(p, __ATOMIC_RELAXED, __HIP_MEMORY_SCOPE_AGENT);
}
__device__ __forceinline__ void llc_store32(unsigned* p, unsigned v) {
  __hip_atomic_store(p, v, __ATOMIC_RELAXED, __HIP_MEMORY_SCOPE_AGENT);
}
__device__ __forceinline__ void llc_store64(u64* p, u64 v) {
  __hip_atomic_store(p, v, __ATOMIC_RELAXED, __HIP_MEMORY_SCOPE_AGENT);
}

// R22 = R21 (721us champion; R14 protocol + vectorized weight gather) with
// three zero-risk latency cuts:
//  1. DEPTH-2 PIPELINED POLL: the serial load->wait->check poll has one flag
//     load in flight -> discovery period = 1 LLC RT. Pipelining (check f0
//     while f1 flies, no s_sleep) halves the period. Stale reads are
//     self-correcting; protocol untouched.
//  2. s=0 ZERO-FILL: iteration 0's staged h0[-1]/h1[-2] are all-zero by
//     definition -- write zeros to LDS instead of 8 LLC loads; skip the
//     (vacuously-true: f >= 0) s=0 poll.
//  3. MEMSET shrunk to the 4 KB flag region. Stale hg across launches is
//     harmless: parity-0 is fully rewritten at s=0 before its first gated
//     read (s=1 poll requires all s=0 stores drained); parity-1 likewise
//     (first read s=2 gated by flag >= 2). Head read gated by flag >= Tz+1.
// Everything else is R21 byte-for-byte (combined u64 h-word, wave0 poll of
// the 8-flag line + barrier A, single tid0 publish after block drain).
__global__ void __launch_bounds__(256, 1)
lstm2(const float* __restrict__ x,
      const float* __restrict__ w_ih0, const float* __restrict__ w_hh0,
      const float* __restrict__ b_ih0, const float* __restrict__ b_hh0,
      const float* __restrict__ w_ih1, const float* __restrict__ w_hh1,
      const float* __restrict__ b_ih1, const float* __restrict__ b_hh1,
      const float* __restrict__ w_lin, const float* __restrict__ b_lin,
      float* __restrict__ out,
      u64* __restrict__ hg, unsigned* __restrict__ flags)
{
  const int blk  = blockIdx.x;
  const int g    = blk >> 3;      // batch group (32)
  const int sl   = blk & 7;       // hidden slice (8)
  const int tid  = threadIdx.x;
  const int w    = tid >> 6;      // wave
  const int lane = tid & 63;
  const int q    = lane >> 4;
  const int l15  = lane & 15;     // batch within group
  const int gbase = g * BT;

  extern __shared__ char smem_raw[];
  short* h0s = (short*)smem_raw;          // [BT][KP] staged h0[s-1], kpos order
  short* h1s = h0s + BT * KP;             // [BT][KP] staged h1[s-2]
  float* xls = (float*)(h1s + BT * KP);   // [BT][XS] x preload
  float* wls = xls + BT * XS;             // [Pz][256] w_lin permuted to kpos order

  // ---- one-time: weights -> register A-fragments (vectorized gather) ----
  // kpos = sl*32 + w*8 + q*2 + j  <->  k_true = sl*32 + w*4 + q + 16*j
  s8v Wf[3][2][8];   // [mat: hh0, ih1, hh1][mti][kt]
  {
    const float* wsrc[3] = {w_hh0, w_ih1, w_hh1};
    #pragma unroll
    for (int mat = 0; mat < 3; ++mat) {
      #pragma unroll
      for (int mti = 0; mti < 2; ++mti) {
        int rr = (w + mti * 4) * 16 + l15;          // rr = unit*4+gate
        int grow = (rr & 3) * Hz + sl * 32 + (rr >> 2);
        const float* p = wsrc[mat] + (size_t)grow * Hz;
        #pragma unroll
        for (int kt = 0; kt < 8; ++kt) {
          // ktrue(j) = kt*32 + q*4 + (j>>1) + 16*(j&1): two aligned float4s
          f4v lo4 = *(const f4v*)(p + kt * 32 + q * 4);
          f4v hi4 = *(const f4v*)(p + kt * 32 + 16 + q * 4);
          s8v f;
          f[0] = f2bf(lo4[0]); f[1] = f2bf(hi4[0]);
          f[2] = f2bf(lo4[1]); f[3] = f2bf(hi4[1]);
          f[4] = f2bf(lo4[2]); f[5] = f2bf(hi4[2]);
          f[6] = f2bf(lo4[3]); f[7] = f2bf(hi4[3]);
          Wf[mat][mti][kt] = f;
        }
      }
    }
  }
  // per-lane epilogue constants: units uA = w*4+q, uB = 16+uA; gates r=0..3
  const int uA = w * 4 + q, uB = 16 + w * 4 + q;
  float wihA[4], wihB[4], b0A[4], b0B[4], b1A[4], b1B[4];
  #pragma unroll
  for (int r = 0; r < 4; ++r) {
    int ga_ = r * Hz + sl * 32 + uA;
    int gb_ = r * Hz + sl * 32 + uB;
    wihA[r] = w_ih0[ga_];              wihB[r] = w_ih0[gb_];
    b0A[r]  = b_ih0[ga_] + b_hh0[ga_]; b0B[r]  = b_ih0[gb_] + b_hh0[gb_];
    b1A[r]  = b_ih1[ga_] + b_hh1[ga_]; b1B[r]  = b_ih1[gb_] + b_hh1[gb_];
  }
  float c0A = 0.f, c0B = 0.f, c1A = 0.f, c1B = 0.f;   // cell states in VGPRs

  // ---- preload x (this group's 16 batches) and permuted w_lin (head) ----
  for (int i = tid; i < BT * (Tz / 4); i += 256) {
    int b = i >> 6, c4 = i & 63;
    f4v v = *(const f4v*)(x + (size_t)(gbase + b) * Tz + c4 * 4);
    *(f4v*)(xls + b * XS + c4 * 4) = v;
  }
  if (sl == 0) {
    for (int i = tid; i < Pz * Hz; i += 256) {
      int p = i >> 8, kpos = i & 255;
      int sl2 = kpos >> 5, w2 = (kpos >> 3) & 3, q2 = (kpos >> 1) & 3, jj = kpos & 1;
      wls[i] = w_lin[p * Hz + sl2 * 32 + w2 * 4 + q2 + 16 * jj];
    }
  }

  const unsigned* myflags = flags + g * 32 + (lane & 7);  // group's 8 flags, one line
  unsigned* myflag = flags + g * 32 + sl;

  for (int s = 0; s <= Tz; ++s) {
    // ---- A: wave0 depth-2 pipelined poll (skip at s=0: vacuously true) ----
    if (w == 0 && s) {
      const unsigned expd = (unsigned)s;
      unsigned f0 = llc_load32(myflags);
      unsigned f1 = llc_load32(myflags);
      for (;;) {
        if (__ballot(f0 >= expd) == ~0ull) break;
        f0 = f1;
        f1 = llc_load32(myflags);
      }
    }
    __syncthreads();   // barrier A: poll verdict gates all waves' stage loads

    // ---- B: stage combined words from parity (s+1)&1 = (s-1)&1 ----
    // word (slw, b, q) = lo32: h0 pair (uA,uB) | hi32: h1 pair, iter s-1
    if (s == 0) {
      // h0[-1] = h1[-2] = 0: zero-fill LDS directly, no exchange reads
      #pragma unroll
      for (int k = 0; k < 4; ++k) {
        int i = tid + k * 256;
        int c = i & 1, b = (i >> 1) & 15, slw = i >> 5;
        *(u64*)(h0s + b * KP + slw * 8 + c * 4) = 0ull;
        *(u64*)(h1s + b * KP + slw * 8 + c * 4) = 0ull;
      }
    } else {
      const u64* sp = hg + (size_t)((s + 1) & 1) * 65536;
      u64 r[8];
      #pragma unroll
      for (int k = 0; k < 4; ++k) {
        int i = tid + k * 256;
        int c = i & 1, b = (i >> 1) & 15, slw = i >> 5;
        size_t gi = ((size_t)slw * Bz + gbase + b) * 4 + 2 * c;
        r[2 * k]     = llc_load64(sp + gi);
        r[2 * k + 1] = llc_load64(sp + gi + 1);
      }
      #pragma unroll
      for (int k = 0; k < 4; ++k) {
        int i = tid + k * 256;
        int c = i & 1, b = (i >> 1) & 15, slw = i >> 5;
        u64 lo = r[2 * k], hi = r[2 * k + 1];
        *(u64*)(h0s + b * KP + slw * 8 + c * 4) =
            (u64)(unsigned)lo | ((u64)(unsigned)hi << 32);
        *(u64*)(h1s + b * KP + slw * 8 + c * 4) =
            (lo >> 32) | ((hi >> 32) << 32);
      }
    }
    __syncthreads();   // sync1: staged LDS visible

    // ---- C: fused MFMA (L0: 16, L1: 32); weights from regs; 16 b128 reads ----
    f4v a0A = {0.f,0.f,0.f,0.f}, a0B = {0.f,0.f,0.f,0.f};
    f4v a1A = {0.f,0.f,0.f,0.f}, a1B = {0.f,0.f,0.f,0.f};
    const short* H0f = h0s + l15 * KP + q * 8;
    const short* H1f = h1s + l15 * KP + q * 8;
    #pragma unroll
    for (int kt = 0; kt < 8; ++kt) {
      s8v h0v = *(const s8v*)(H0f + kt * 32);
      s8v h1v = *(const s8v*)(H1f + kt * 32);
      a0A = __builtin_amdgcn_mfma_f32_16x16x32_bf16(Wf[0][0][kt], h0v, a0A, 0, 0, 0);
      a0B = __builtin_amdgcn_mfma_f32_16x16x32_bf16(Wf[0][1][kt], h0v, a0B, 0, 0, 0);
      a1A = __builtin_amdgcn_mfma_f32_16x16x32_bf16(Wf[1][0][kt], h0v, a1A, 0, 0, 0);
      a1B = __builtin_amdgcn_mfma_f32_16x16x32_bf16(Wf[1][1][kt], h0v, a1B, 0, 0, 0);
      a1A = __builtin_amdgcn_mfma_f32_16x16x32_bf16(Wf[2][0][kt], h1v, a1A, 0, 0, 0);
      a1B = __builtin_amdgcn_mfma_f32_16x16x32_bf16(Wf[2][1][kt], h1v, a1B, 0, 0, 0);
    }

    // ---- D: in-register epilogues -> one packed u32 per layer ----
    unsigned pk0 = 0, pk1 = 0;
    if (s < Tz) {
      float xv = xls[l15 * XS + s];
      float iA = sigm  (a0A[0] + xv * wihA[0] + b0A[0]);
      float fA = sigm  (a0A[1] + xv * wihA[1] + b0A[1]);
      float gA = tanh_f(a0A[2] + xv * wihA[2] + b0A[2]);
      float oA = sigm  (a0A[3] + xv * wihA[3] + b0A[3]);
      c0A = fA * c0A + iA * gA;
      float iB = sigm  (a0B[0] + xv * wihB[0] + b0B[0]);
      float fB = sigm  (a0B[1] + xv * wihB[1] + b0B[1]);
      float gB = tanh_f(a0B[2] + xv * wihB[2] + b0B[2]);
      float oB = sigm  (a0B[3] + xv * wihB[3] + b0B[3]);
      c0B = fB * c0B + iB * gB;
      pk0 = (unsigned)(unsigned short)f2bf(oA * tanh_f(c0A))
          | ((unsigned)(unsigned short)f2bf(oB * tanh_f(c0B)) << 16);
    }
    if (s >= 1) {
      float iA = sigm  (a1A[0] + b1A[0]);
      float fA = sigm  (a1A[1] + b1A[1]);
      float gA = tanh_f(a1A[2] + b1A[2]);
      float oA = sigm  (a1A[3] + b1A[3]);
      c1A = fA * c1A + iA * gA;
      float iB = sigm  (a1B[0] + b1B[0]);
      float fB = sigm  (a1B[1] + b1B[1]);
      float gB = tanh_f(a1B[2] + b1B[2]);
      float oB = sigm  (a1B[3] + b1B[3]);
      c1B = fB * c1B + iB * gB;
      pk1 = (unsigned)(unsigned short)f2bf(oA * tanh_f(c1A))
          | ((unsigned)(unsigned short)f2bf(oB * tanh_f(c1B)) << 16);
    }

    // ---- E: ONE combined coalesced store (unconditional) ----
    // pk1=0 at s=0 is the true h1[-1]=0; pk0=0 at s=Tz is never read.
    {
      size_t base = (size_t)(sl * 4 + w) * 2048 + (size_t)(gbase + l15) * 4 + q;
      llc_store64(hg + (size_t)(s & 1) * 65536 + base,
                  (u64)pk0 | ((u64)pk1 << 32));
    }

    // ---- F: drain (per-wave vmcnt(0) inside __syncthreads) + publish ----
    __syncthreads();
    if (tid == 0)
      llc_store32(myflag, (unsigned)(s + 1));
  }

  // ---- final head (sl==0 blocks): out = h1[Tz-1] @ w_lin^T + b_lin ----
  // h1[Tz-1] = hi32 halves of combined words written at iter Tz, parity 0.
  if (sl == 0) {
    {
      const unsigned expd = (unsigned)(Tz + 1);
      unsigned f0 = llc_load32(myflags);
      unsigned f1 = llc_load32(myflags);
      for (;;) {
        if (__ballot(f0 >= expd) == ~0ull) break;
        f0 = f1;
        f1 = llc_load32(myflags);
      }
    }
    const u64* sp = hg + (size_t)(Tz & 1) * 65536;   // parity 0
    for (int k = 0; k < 4; ++k) {
      int i = tid + k * 256;
      int c = i & 1, b = (i >> 1) & 15, slw = i >> 5;
      size_t gi = ((size_t)slw * Bz + gbase + b) * 4 + 2 * c;
      u64 lo = llc_load64(sp + gi);
      u64 hi = llc_load64(sp + gi + 1);
      *(u64*)(h0s + b * KP + slw * 8 + c * 4) = (lo >> 32) | ((hi >> 32) << 32);
    }
    __syncthreads();
    for (int i = tid; i < BT * Pz; i += 256) {
      int b = i / Pz, p = i - b * Pz;
      const float* wr = wls + p * Hz;
      float acc = b_lin[p];
      for (int kk = 0; kk < Hz; ++kk)
        acc += bf2f(h0s[b * KP + kk]) * wr[kk];   // both in kpos order
      out[(gbase + b) * Pz + p] = acc;
    }
  }
}

extern "C" void kernel_launch(void* const* d_in, const int* in_sizes, int n_in,
                              void* d_out, int out_size, void* d_ws, size_t ws_size,
                              hipStream_t stream) {
  const float* x     = (const float*)d_in[0];
  const float* w_ih0 = (const float*)d_in[1];
  const float* w_hh0 = (const float*)d_in[2];
  const float* b_ih0 = (const float*)d_in[3];
  const float* b_hh0 = (const float*)d_in[4];
  const float* w_ih1 = (const float*)d_in[5];
  const float* w_hh1 = (const float*)d_in[6];
  const float* b_ih1 = (const float*)d_in[7];
  const float* b_hh1 = (const float*)d_in[8];
  const float* w_lin = (const float*)d_in[9];
  const float* b_lin = (const float*)d_in[10];
  float* out = (float*)d_out;

  unsigned char* ws = (unsigned char*)d_ws;
  u64* hg         = (u64*)ws;                          // [2][65536] u64 (512 KB/parity)
  unsigned* flags = (unsigned*)(ws + (1 << 20));       // [32 groups][32] u32 (8 used)
  // Only the flags need zeroing ("0 steps completed"). hg needs NO init:
  // s=0 zero-fills LDS directly; every hg slot is rewritten before its
  // first flag-gated read (see kernel header).
  hipMemsetAsync(ws + (1 << 20), 0, 4096, stream);

  size_t lds_bytes = (size_t)(2 * BT) * KP * 2     // h staging
                   + (size_t)(BT * XS) * 4         // x preload
                   + (size_t)(Pz * Hz) * 4;        // permuted w_lin (head)
  hipFuncSetAttribute((const void*)lstm2,
                      hipFuncAttributeMaxDynamicSharedMemorySize, (int)lds_bytes);
  lstm2<<<GB * GS, 256, lds_bytes, stream>>>(x, w_ih0, w_hh0, b_ih0, b_hh0,
                                             w_ih1, w_hh1, b_ih1, b_hh1,
                                             w_lin, b_lin, out, hg, flags);
}

// Round 14
// 763.156 us; speedup vs baseline: 1.0153x; 1.0153x over previous
//
#include <hip/hip_runtime.h>

// Problem constants
constexpr int Bz = 512;   // batch
constexpr int Tz = 256;   // seq len
constexpr int Hz = 256;   // hidden
constexpr int Pz = 14;    // predict dim
constexpr int GB = 32;    // batch groups
constexpr int GS = 8;     // hidden slices per group
constexpr int BT = 16;    // batch per group (512/32)
constexpr int KP = 264;   // LDS h row stride (shorts)
constexpr int XS = 260;   // x LDS row stride (floats)

typedef short s8v __attribute__((ext_vector_type(8)));
typedef float f4v __attribute__((ext_vector_type(4)));
typedef unsigned long long u64;

__device__ __forceinline__ short f2bf(float f) {
  unsigned u = __float_as_uint(f);
  u = (u + 0x7fffu + ((u >> 16) & 1u)) >> 16;   // RNE
  return (short)u;
}
__device__ __forceinline__ float bf2f(short s) {
  return __uint_as_float(((unsigned)(unsigned short)s) << 16);
}
// Fast gates (R11/R14-proven numerics: identical absmax to libm path)
__device__ __forceinline__ float sigm(float v) {
  return __builtin_amdgcn_rcpf(1.0f + __builtin_amdgcn_exp2f(-1.442695041f * v));
}
__device__ __forceinline__ float tanh_f(float v) {
  return 1.0f - 2.0f * __builtin_amdgcn_rcpf(__builtin_amdgcn_exp2f(2.885390082f * v) + 1.0f);
}

__device__ __forceinline__ u64 llc_load64(const u64* p) {
  return __hip_atomic_load(p, __ATOMIC_RELAXED, __HIP_MEMORY_SCOPE_AGENT);
}
__device__ __forceinline__ unsigned llc_load32(const unsigned* p) {
  return __hip_atomic_load(p, __ATOMIC_RELAXED, __HIP_MEMORY_SCOPE_AGENT);
}
__device__ __forceinline__ void llc_store32(unsigned* p, unsigned v) {
  __hip_atomic_store(p, v, __ATOMIC_RELAXED, __HIP_MEMORY_SCOPE_AGENT);
}
__device__ __forceinline__ void llc_store64(u64* p, u64 v) {
  __hip_atomic_store(p, v, __ATOMIC_RELAXED, __HIP_MEMORY_SCOPE_AGENT);
}

// R23 = R21 (721us champion) + ONLY the two provably-safe cuts from R22:
//   - s=0 ZERO-FILL: iteration 0 stages zeros directly in LDS (h[-1]=0),
//     skipping 8 LLC loads and the vacuous s=0 poll.
//   - MEMSET shrunk to the 4 KB flag region (hg needs no init: every slot
//     is rewritten before its first flag-gated read).
// R22's depth-2 NO-SLEEP poll is REVERTED: it regressed steady 683->723us.
// Lesson (3rd confirmation after R10/R13): unthrottled polling contends at
// the TCC with the data/flag stores it waits for -- s_sleep(1) throttling
// is load-bearing. This build isolates the poll variable vs R21 exactly.
//
// Protocol (R14-proven; every leg experimentally load-bearing):
//   wave0 throttled poll of the group's 8-flag line -> barrier A ->
//   8x u64 combined-word stage -> sync1 -> 48 MFMA + in-register epilogue ->
//   ONE combined u64 store -> F-barrier (per-wave vmcnt(0) drain) ->
//   single tid0 flag publish.
// Family post-mortem (R10-R22): in-band tags, per-wave flags, atomic ctrs,
// wide blocks, layer-split, speculative loads, unthrottled polls -- ALL
// regressed. Remaining ~2.6us/step is the synchronization-latency floor
// (publish + discover-RT + stage-RT + 0.7us compute); HBM 13%, MfmaUtil
// 12.5% -- latency-bound, not a counter roofline.
__global__ void __launch_bounds__(256, 1)
lstm2(const float* __restrict__ x,
      const float* __restrict__ w_ih0, const float* __restrict__ w_hh0,
      const float* __restrict__ b_ih0, const float* __restrict__ b_hh0,
      const float* __restrict__ w_ih1, const float* __restrict__ w_hh1,
      const float* __restrict__ b_ih1, const float* __restrict__ b_hh1,
      const float* __restrict__ w_lin, const float* __restrict__ b_lin,
      float* __restrict__ out,
      u64* __restrict__ hg, unsigned* __restrict__ flags)
{
  const int blk  = blockIdx.x;
  const int g    = blk >> 3;      // batch group (32)
  const int sl   = blk & 7;       // hidden slice (8)
  const int tid  = threadIdx.x;
  const int w    = tid >> 6;      // wave
  const int lane = tid & 63;
  const int q    = lane >> 4;
  const int l15  = lane & 15;     // batch within group
  const int gbase = g * BT;

  extern __shared__ char smem_raw[];
  short* h0s = (short*)smem_raw;          // [BT][KP] staged h0[s-1], kpos order
  short* h1s = h0s + BT * KP;             // [BT][KP] staged h1[s-2]
  float* xls = (float*)(h1s + BT * KP);   // [BT][XS] x preload
  float* wls = xls + BT * XS;             // [Pz][256] w_lin permuted to kpos order

  // ---- one-time: weights -> register A-fragments (vectorized gather) ----
  // kpos = sl*32 + w*8 + q*2 + j  <->  k_true = sl*32 + w*4 + q + 16*j
  s8v Wf[3][2][8];   // [mat: hh0, ih1, hh1][mti][kt]
  {
    const float* wsrc[3] = {w_hh0, w_ih1, w_hh1};
    #pragma unroll
    for (int mat = 0; mat < 3; ++mat) {
      #pragma unroll
      for (int mti = 0; mti < 2; ++mti) {
        int rr = (w + mti * 4) * 16 + l15;          // rr = unit*4+gate
        int grow = (rr & 3) * Hz + sl * 32 + (rr >> 2);
        const float* p = wsrc[mat] + (size_t)grow * Hz;
        #pragma unroll
        for (int kt = 0; kt < 8; ++kt) {
          // ktrue(j) = kt*32 + q*4 + (j>>1) + 16*(j&1): two aligned float4s
          f4v lo4 = *(const f4v*)(p + kt * 32 + q * 4);
          f4v hi4 = *(const f4v*)(p + kt * 32 + 16 + q * 4);
          s8v f;
          f[0] = f2bf(lo4[0]); f[1] = f2bf(hi4[0]);
          f[2] = f2bf(lo4[1]); f[3] = f2bf(hi4[1]);
          f[4] = f2bf(lo4[2]); f[5] = f2bf(hi4[2]);
          f[6] = f2bf(lo4[3]); f[7] = f2bf(hi4[3]);
          Wf[mat][mti][kt] = f;
        }
      }
    }
  }
  // per-lane epilogue constants: units uA = w*4+q, uB = 16+uA; gates r=0..3
  const int uA = w * 4 + q, uB = 16 + w * 4 + q;
  float wihA[4], wihB[4], b0A[4], b0B[4], b1A[4], b1B[4];
  #pragma unroll
  for (int r = 0; r < 4; ++r) {
    int ga_ = r * Hz + sl * 32 + uA;
    int gb_ = r * Hz + sl * 32 + uB;
    wihA[r] = w_ih0[ga_];              wihB[r] = w_ih0[gb_];
    b0A[r]  = b_ih0[ga_] + b_hh0[ga_]; b0B[r]  = b_ih0[gb_] + b_hh0[gb_];
    b1A[r]  = b_ih1[ga_] + b_hh1[ga_]; b1B[r]  = b_ih1[gb_] + b_hh1[gb_];
  }
  float c0A = 0.f, c0B = 0.f, c1A = 0.f, c1B = 0.f;   // cell states in VGPRs

  // ---- preload x (this group's 16 batches) and permuted w_lin (head) ----
  for (int i = tid; i < BT * (Tz / 4); i += 256) {
    int b = i >> 6, c4 = i & 63;
    f4v v = *(const f4v*)(x + (size_t)(gbase + b) * Tz + c4 * 4);
    *(f4v*)(xls + b * XS + c4 * 4) = v;
  }
  if (sl == 0) {
    for (int i = tid; i < Pz * Hz; i += 256) {
      int p = i >> 8, kpos = i & 255;
      int sl2 = kpos >> 5, w2 = (kpos >> 3) & 3, q2 = (kpos >> 1) & 3, jj = kpos & 1;
      wls[i] = w_lin[p * Hz + sl2 * 32 + w2 * 4 + q2 + 16 * jj];
    }
  }

  const unsigned* myflags = flags + g * 32 + (lane & 7);  // group's 8 flags, one line
  unsigned* myflag = flags + g * 32 + sl;

  for (int s = 0; s <= Tz; ++s) {
    // ---- A: wave0 throttled poll (R21-proven); skip at s=0 (vacuous) ----
    if (w == 0 && s) {
      const unsigned expd = (unsigned)s;
      unsigned f = llc_load32(myflags);
      while (__ballot(f >= expd) != ~0ull) {
        __builtin_amdgcn_s_sleep(1);
        f = llc_load32(myflags);
      }
    }
    __syncthreads();   // barrier A: poll verdict gates all waves' stage loads

    // ---- B: stage combined words from parity (s+1)&1 = (s-1)&1 ----
    // word (slw, b, q) = lo32: h0 pair (uA,uB) | hi32: h1 pair, iter s-1
    if (s == 0) {
      // h0[-1] = h1[-2] = 0: zero-fill LDS directly, no exchange reads
      #pragma unroll
      for (int k = 0; k < 4; ++k) {
        int i = tid + k * 256;
        int c = i & 1, b = (i >> 1) & 15, slw = i >> 5;
        *(u64*)(h0s + b * KP + slw * 8 + c * 4) = 0ull;
        *(u64*)(h1s + b * KP + slw * 8 + c * 4) = 0ull;
      }
    } else {
      const u64* sp = hg + (size_t)((s + 1) & 1) * 65536;
      u64 r[8];
      #pragma unroll
      for (int k = 0; k < 4; ++k) {
        int i = tid + k * 256;
        int c = i & 1, b = (i >> 1) & 15, slw = i >> 5;
        size_t gi = ((size_t)slw * Bz + gbase + b) * 4 + 2 * c;
        r[2 * k]     = llc_load64(sp + gi);
        r[2 * k + 1] = llc_load64(sp + gi + 1);
      }
      #pragma unroll
      for (int k = 0; k < 4; ++k) {
        int i = tid + k * 256;
        int c = i & 1, b = (i >> 1) & 15, slw = i >> 5;
        u64 lo = r[2 * k], hi = r[2 * k + 1];
        *(u64*)(h0s + b * KP + slw * 8 + c * 4) =
            (u64)(unsigned)lo | ((u64)(unsigned)hi << 32);
        *(u64*)(h1s + b * KP + slw * 8 + c * 4) =
            (lo >> 32) | ((hi >> 32) << 32);
      }
    }
    __syncthreads();   // sync1: staged LDS visible

    // ---- C: fused MFMA (L0: 16, L1: 32); weights from regs; 16 b128 reads ----
    f4v a0A = {0.f,0.f,0.f,0.f}, a0B = {0.f,0.f,0.f,0.f};
    f4v a1A = {0.f,0.f,0.f,0.f}, a1B = {0.f,0.f,0.f,0.f};
    const short* H0f = h0s + l15 * KP + q * 8;
    const short* H1f = h1s + l15 * KP + q * 8;
    #pragma unroll
    for (int kt = 0; kt < 8; ++kt) {
      s8v h0v = *(const s8v*)(H0f + kt * 32);
      s8v h1v = *(const s8v*)(H1f + kt * 32);
      a0A = __builtin_amdgcn_mfma_f32_16x16x32_bf16(Wf[0][0][kt], h0v, a0A, 0, 0, 0);
      a0B = __builtin_amdgcn_mfma_f32_16x16x32_bf16(Wf[0][1][kt], h0v, a0B, 0, 0, 0);
      a1A = __builtin_amdgcn_mfma_f32_16x16x32_bf16(Wf[1][0][kt], h0v, a1A, 0, 0, 0);
      a1B = __builtin_amdgcn_mfma_f32_16x16x32_bf16(Wf[1][1][kt], h0v, a1B, 0, 0, 0);
      a1A = __builtin_amdgcn_mfma_f32_16x16x32_bf16(Wf[2][0][kt], h1v, a1A, 0, 0, 0);
      a1B = __builtin_amdgcn_mfma_f32_16x16x32_bf16(Wf[2][1][kt], h1v, a1B, 0, 0, 0);
    }

    // ---- D: in-register epilogues -> one packed u32 per layer ----
    unsigned pk0 = 0, pk1 = 0;
    if (s < Tz) {
      float xv = xls[l15 * XS + s];
      float iA = sigm  (a0A[0] + xv * wihA[0] + b0A[0]);
      float fA = sigm  (a0A[1] + xv * wihA[1] + b0A[1]);
      float gA = tanh_f(a0A[2] + xv * wihA[2] + b0A[2]);
      float oA = sigm  (a0A[3] + xv * wihA[3] + b0A[3]);
      c0A = fA * c0A + iA * gA;
      float iB = sigm  (a0B[0] + xv * wihB[0] + b0B[0]);
      float fB = sigm  (a0B[1] + xv * wihB[1] + b0B[1]);
      float gB = tanh_f(a0B[2] + xv * wihB[2] + b0B[2]);
      float oB = sigm  (a0B[3] + xv * wihB[3] + b0B[3]);
      c0B = fB * c0B + iB * gB;
      pk0 = (unsigned)(unsigned short)f2bf(oA * tanh_f(c0A))
          | ((unsigned)(unsigned short)f2bf(oB * tanh_f(c0B)) << 16);
    }
    if (s >= 1) {
      float iA = sigm  (a1A[0] + b1A[0]);
      float fA = sigm  (a1A[1] + b1A[1]);
      float gA = tanh_f(a1A[2] + b1A[2]);
      float oA = sigm  (a1A[3] + b1A[3]);
      c1A = fA * c1A + iA * gA;
      float iB = sigm  (a1B[0] + b1B[0]);
      float fB = sigm  (a1B[1] + b1B[1]);
      float gB = tanh_f(a1B[2] + b1B[2]);
      float oB = sigm  (a1B[3] + b1B[3]);
      c1B = fB * c1B + iB * gB;
      pk1 = (unsigned)(unsigned short)f2bf(oA * tanh_f(c1A))
          | ((unsigned)(unsigned short)f2bf(oB * tanh_f(c1B)) << 16);
    }

    // ---- E: ONE combined coalesced store (unconditional) ----
    // pk1=0 at s=0 is the true h1[-1]=0; pk0=0 at s=Tz is never read.
    {
      size_t base = (size_t)(sl * 4 + w) * 2048 + (size_t)(gbase + l15) * 4 + q;
      llc_store64(hg + (size_t)(s & 1) * 65536 + base,
                  (u64)pk0 | ((u64)pk1 << 32));
    }

    // ---- F: drain (per-wave vmcnt(0) inside __syncthreads) + publish ----
    __syncthreads();
    if (tid == 0)
      llc_store32(myflag, (unsigned)(s + 1));
  }

  // ---- final head (sl==0 blocks): out = h1[Tz-1] @ w_lin^T + b_lin ----
  // h1[Tz-1] = hi32 halves of combined words written at iter Tz, parity 0.
  if (sl == 0) {
    {
      const unsigned expd = (unsigned)(Tz + 1);
      unsigned f = llc_load32(myflags);
      while (__ballot(f >= expd) != ~0ull) {
        __builtin_amdgcn_s_sleep(1);
        f = llc_load32(myflags);
      }
    }
    const u64* sp = hg + (size_t)(Tz & 1) * 65536;   // parity 0
    for (int k = 0; k < 4; ++k) {
      int i = tid + k * 256;
      int c = i & 1, b = (i >> 1) & 15, slw = i >> 5;
      size_t gi = ((size_t)slw * Bz + gbase + b) * 4 + 2 * c;
      u64 lo = llc_load64(sp + gi);
      u64 hi = llc_load64(sp + gi + 1);
      *(u64*)(h0s + b * KP + slw * 8 + c * 4) = (lo >> 32) | ((hi >> 32) << 32);
    }
    __syncthreads();
    for (int i = tid; i < BT * Pz; i += 256) {
      int b = i / Pz, p = i - b * Pz;
      const float* wr = wls + p * Hz;
      float acc = b_lin[p];
      for (int kk = 0; kk < Hz; ++kk)
        acc += bf2f(h0s[b * KP + kk]) * wr[kk];   // both in kpos order
      out[(gbase + b) * Pz + p] = acc;
    }
  }
}

extern "C" void kernel_launch(void* const* d_in, const int* in_sizes, int n_in,
                              void* d_out, int out_size, void* d_ws, size_t ws_size,
                              hipStream_t stream) {
  const float* x     = (const float*)d_in[0];
  const float* w_ih0 = (const float*)d_in[1];
  const float* w_hh0 = (const float*)d_in[2];
  const float* b_ih0 = (const float*)d_in[3];
  const float* b_hh0 = (const float*)d_in[4];
  const float* w_ih1 = (const float*)d_in[5];
  const float* w_hh1 = (const float*)d_in[6];
  const float* b_ih1 = (const float*)d_in[7];
  const float* b_hh1 = (const float*)d_in[8];
  const float* w_lin = (const float*)d_in[9];
  const float* b_lin = (const float*)d_in[10];
  float* out = (float*)d_out;

  unsigned char* ws = (unsigned char*)d_ws;
  u64* hg         = (u64*)ws;                          // [2][65536] u64 (512 KB/parity)
  unsigned* flags = (unsigned*)(ws + (1 << 20));       // [32 groups][32] u32 (8 used)
  // Only the flags need zeroing ("0 steps completed"). hg needs NO init:
  // s=0 zero-fills LDS directly; every hg slot is rewritten before its
  // first flag-gated read (see kernel header).
  hipMemsetAsync(ws + (1 << 20), 0, 4096, stream);

  size_t lds_bytes = (size_t)(2 * BT) * KP * 2     // h staging
                   + (size_t)(BT * XS) * 4         // x preload
                   + (size_t)(Pz * Hz) * 4;        // permuted w_lin (head)
  hipFuncSetAttribute((const void*)lstm2,
                      hipFuncAttributeMaxDynamicSharedMemorySize, (int)lds_bytes);
  lstm2<<<GB * GS, 256, lds_bytes, stream>>>(x, w_ih0, w_hh0, b_ih0, b_hh0,
                                             w_ih1, w_hh1, b_ih1, b_hh1,
                                             w_lin, b_lin, out, hg, flags);
}

// Round 15
// 717.608 us; speedup vs baseline: 1.0798x; 1.0635x over previous
//
#include <hip/hip_runtime.h>

// Problem constants
constexpr int Bz = 512;   // batch
constexpr int Tz = 256;   // seq len
constexpr int Hz = 256;   // hidden
constexpr int Pz = 14;    // predict dim
constexpr int GB = 32;    // batch groups
constexpr int GS = 8;     // hidden slices per group
constexpr int BT = 16;    // batch per group (512/32)
constexpr int KP = 264;   // LDS h row stride (shorts)
constexpr int XS = 260;   // x LDS row stride (floats)

typedef short s8v __attribute__((ext_vector_type(8)));
typedef float f4v __attribute__((ext_vector_type(4)));
typedef unsigned long long u64;

__device__ __forceinline__ short f2bf(float f) {
  unsigned u = __float_as_uint(f);
  u = (u + 0x7fffu + ((u >> 16) & 1u)) >> 16;   // RNE
  return (short)u;
}
__device__ __forceinline__ float bf2f(short s) {
  return __uint_as_float(((unsigned)(unsigned short)s) << 16);
}
// Fast gates (R11/R14-proven numerics: identical absmax to libm path)
__device__ __forceinline__ float sigm(float v) {
  return __builtin_amdgcn_rcpf(1.0f + __builtin_amdgcn_exp2f(-1.442695041f * v));
}
__device__ __forceinline__ float tanh_f(float v) {
  return 1.0f - 2.0f * __builtin_amdgcn_rcpf(__builtin_amdgcn_exp2f(2.885390082f * v) + 1.0f);
}

__device__ __forceinline__ u64 llc_load64(const u64* p) {
  return __hip_atomic_load(p, __ATOMIC_RELAXED, __HIP_MEMORY_SCOPE_AGENT);
}
__device__ __forceinline__ unsigned llc_load32(const unsigned* p) {
  return __hip_atomic_load(p, __ATOMIC_RELAXED, __HIP_MEMORY_SCOPE_AGENT);
}
__device__ __forceinline__ void llc_store32(unsigned* p, unsigned v) {
  __hip_atomic_store(p, v, __ATOMIC_RELAXED, __HIP_MEMORY_SCOPE_AGENT);
}
__device__ __forceinline__ void llc_store64(u64* p, u64 v) {
  __hip_atomic_store(p, v, __ATOMIC_RELAXED, __HIP_MEMORY_SCOPE_AGENT);
}

// R24 = R21 BYTE-FOR-BYTE (the session's best measured build: 721.04us wall,
// 681-686us steady). Decisive A/B after R23 falsified the R22 poll
// attribution: R22 (no-sleep poll + s0-zerofill + memset-shrink) = 723
// steady, R23 (throttled poll + s0-zerofill + memset-shrink) = 722 steady.
// The shared "safe cuts" (s=0 branch in the hot loop / hg memset removal)
// -- or cross-acquisition machine variance -- caused the 683->722 delta,
// NOT the poll. This build removes both cuts, restoring the exact R21
// binary: full 1MB+4KB memset, uniform loop (s=0 polls vacuously and
// stages from zeroed hg), no in-loop branch.
//
// Protocol (R14-proven; every leg experimentally load-bearing across
// R10/R13/R15-R20/R22): wave0 throttled poll of the group's 8-flag line ->
// barrier A -> 8x u64 combined-word stage -> sync1 -> 48 MFMA + in-register
// epilogue -> ONE combined u64 store -> F-barrier (per-wave vmcnt(0) drain)
// -> single tid0 flag publish. Remaining ~2.6us/step is the
// synchronization-latency floor (publish + discover-RT + stage-RT + 0.7us
// compute); HBM 13%, MfmaUtil 12.5% -- latency-bound, not a counter
// roofline.
__global__ void __launch_bounds__(256, 1)
lstm2(const float* __restrict__ x,
      const float* __restrict__ w_ih0, const float* __restrict__ w_hh0,
      const float* __restrict__ b_ih0, const float* __restrict__ b_hh0,
      const float* __restrict__ w_ih1, const float* __restrict__ w_hh1,
      const float* __restrict__ b_ih1, const float* __restrict__ b_hh1,
      const float* __restrict__ w_lin, const float* __restrict__ b_lin,
      float* __restrict__ out,
      u64* __restrict__ hg, unsigned* __restrict__ flags)
{
  const int blk  = blockIdx.x;
  const int g    = blk >> 3;      // batch group (32)
  const int sl   = blk & 7;       // hidden slice (8)
  const int tid  = threadIdx.x;
  const int w    = tid >> 6;      // wave
  const int lane = tid & 63;
  const int q    = lane >> 4;
  const int l15  = lane & 15;     // batch within group
  const int gbase = g * BT;

  extern __shared__ char smem_raw[];
  short* h0s = (short*)smem_raw;          // [BT][KP] staged h0[s-1], kpos order
  short* h1s = h0s + BT * KP;             // [BT][KP] staged h1[s-2]
  float* xls = (float*)(h1s + BT * KP);   // [BT][XS] x preload
  float* wls = xls + BT * XS;             // [Pz][256] w_lin permuted to kpos order

  // ---- one-time: weights -> register A-fragments (vectorized gather) ----
  // kpos = sl*32 + w*8 + q*2 + j  <->  k_true = sl*32 + w*4 + q + 16*j
  s8v Wf[3][2][8];   // [mat: hh0, ih1, hh1][mti][kt]
  {
    const float* wsrc[3] = {w_hh0, w_ih1, w_hh1};
    #pragma unroll
    for (int mat = 0; mat < 3; ++mat) {
      #pragma unroll
      for (int mti = 0; mti < 2; ++mti) {
        int rr = (w + mti * 4) * 16 + l15;          // rr = unit*4+gate
        int grow = (rr & 3) * Hz + sl * 32 + (rr >> 2);
        const float* p = wsrc[mat] + (size_t)grow * Hz;
        #pragma unroll
        for (int kt = 0; kt < 8; ++kt) {
          // ktrue(j) = kt*32 + q*4 + (j>>1) + 16*(j&1): two aligned float4s
          f4v lo4 = *(const f4v*)(p + kt * 32 + q * 4);
          f4v hi4 = *(const f4v*)(p + kt * 32 + 16 + q * 4);
          s8v f;
          f[0] = f2bf(lo4[0]); f[1] = f2bf(hi4[0]);
          f[2] = f2bf(lo4[1]); f[3] = f2bf(hi4[1]);
          f[4] = f2bf(lo4[2]); f[5] = f2bf(hi4[2]);
          f[6] = f2bf(lo4[3]); f[7] = f2bf(hi4[3]);
          Wf[mat][mti][kt] = f;
        }
      }
    }
  }
  // per-lane epilogue constants: units uA = w*4+q, uB = 16+uA; gates r=0..3
  const int uA = w * 4 + q, uB = 16 + w * 4 + q;
  float wihA[4], wihB[4], b0A[4], b0B[4], b1A[4], b1B[4];
  #pragma unroll
  for (int r = 0; r < 4; ++r) {
    int ga_ = r * Hz + sl * 32 + uA;
    int gb_ = r * Hz + sl * 32 + uB;
    wihA[r] = w_ih0[ga_];              wihB[r] = w_ih0[gb_];
    b0A[r]  = b_ih0[ga_] + b_hh0[ga_]; b0B[r]  = b_ih0[gb_] + b_hh0[gb_];
    b1A[r]  = b_ih1[ga_] + b_hh1[ga_]; b1B[r]  = b_ih1[gb_] + b_hh1[gb_];
  }
  float c0A = 0.f, c0B = 0.f, c1A = 0.f, c1B = 0.f;   // cell states in VGPRs

  // ---- preload x (this group's 16 batches) and permuted w_lin (head) ----
  for (int i = tid; i < BT * (Tz / 4); i += 256) {
    int b = i >> 6, c4 = i & 63;
    f4v v = *(const f4v*)(x + (size_t)(gbase + b) * Tz + c4 * 4);
    *(f4v*)(xls + b * XS + c4 * 4) = v;
  }
  if (sl == 0) {
    for (int i = tid; i < Pz * Hz; i += 256) {
      int p = i >> 8, kpos = i & 255;
      int sl2 = kpos >> 5, w2 = (kpos >> 3) & 3, q2 = (kpos >> 1) & 3, jj = kpos & 1;
      wls[i] = w_lin[p * Hz + sl2 * 32 + w2 * 4 + q2 + 16 * jj];
    }
  }

  const unsigned* myflags = flags + g * 32 + (lane & 7);  // group's 8 flags, one line
  unsigned* myflag = flags + g * 32 + sl;

  for (int s = 0; s <= Tz; ++s) {
    // ---- A: wave0 polls: all 8 producers completed step s-1; barrier gates rest ----
    if (w == 0) {
      const unsigned expd = (unsigned)s;
      unsigned f = llc_load32(myflags);
      while (__ballot(f >= expd) != ~0ull) {
        __builtin_amdgcn_s_sleep(1);
        f = llc_load32(myflags);
      }
    }
    __syncthreads();   // barrier A: poll verdict gates all waves' stage loads

    // ---- B: stage combined words from parity (s+1)&1 = (s-1)&1 ----
    // word (slw, b, q) = lo32: h0 pair (uA,uB) | hi32: h1 pair, iter s-1
    {
      const u64* sp = hg + (size_t)((s + 1) & 1) * 65536;
      u64 r[8];
      #pragma unroll
      for (int k = 0; k < 4; ++k) {
        int i = tid + k * 256;
        int c = i & 1, b = (i >> 1) & 15, slw = i >> 5;
        size_t gi = ((size_t)slw * Bz + gbase + b) * 4 + 2 * c;
        r[2 * k]     = llc_load64(sp + gi);
        r[2 * k + 1] = llc_load64(sp + gi + 1);
      }
      #pragma unroll
      for (int k = 0; k < 4; ++k) {
        int i = tid + k * 256;
        int c = i & 1, b = (i >> 1) & 15, slw = i >> 5;
        u64 lo = r[2 * k], hi = r[2 * k + 1];
        *(u64*)(h0s + b * KP + slw * 8 + c * 4) =
            (u64)(unsigned)lo | ((u64)(unsigned)hi << 32);
        *(u64*)(h1s + b * KP + slw * 8 + c * 4) =
            (lo >> 32) | ((hi >> 32) << 32);
      }
    }
    __syncthreads();   // sync1: staged LDS visible

    // ---- C: fused MFMA (L0: 16, L1: 32); weights from regs; 16 b128 reads ----
    f4v a0A = {0.f,0.f,0.f,0.f}, a0B = {0.f,0.f,0.f,0.f};
    f4v a1A = {0.f,0.f,0.f,0.f}, a1B = {0.f,0.f,0.f,0.f};
    const short* H0f = h0s + l15 * KP + q * 8;
    const short* H1f = h1s + l15 * KP + q * 8;
    #pragma unroll
    for (int kt = 0; kt < 8; ++kt) {
      s8v h0v = *(const s8v*)(H0f + kt * 32);
      s8v h1v = *(const s8v*)(H1f + kt * 32);
      a0A = __builtin_amdgcn_mfma_f32_16x16x32_bf16(Wf[0][0][kt], h0v, a0A, 0, 0, 0);
      a0B = __builtin_amdgcn_mfma_f32_16x16x32_bf16(Wf[0][1][kt], h0v, a0B, 0, 0, 0);
      a1A = __builtin_amdgcn_mfma_f32_16x16x32_bf16(Wf[1][0][kt], h0v, a1A, 0, 0, 0);
      a1B = __builtin_amdgcn_mfma_f32_16x16x32_bf16(Wf[1][1][kt], h0v, a1B, 0, 0, 0);
      a1A = __builtin_amdgcn_mfma_f32_16x16x32_bf16(Wf[2][0][kt], h1v, a1A, 0, 0, 0);
      a1B = __builtin_amdgcn_mfma_f32_16x16x32_bf16(Wf[2][1][kt], h1v, a1B, 0, 0, 0);
    }

    // ---- D: in-register epilogues -> one packed u32 per layer ----
    unsigned pk0 = 0, pk1 = 0;
    if (s < Tz) {
      float xv = xls[l15 * XS + s];
      float iA = sigm  (a0A[0] + xv * wihA[0] + b0A[0]);
      float fA = sigm  (a0A[1] + xv * wihA[1] + b0A[1]);
      float gA = tanh_f(a0A[2] + xv * wihA[2] + b0A[2]);
      float oA = sigm  (a0A[3] + xv * wihA[3] + b0A[3]);
      c0A = fA * c0A + iA * gA;
      float iB = sigm  (a0B[0] + xv * wihB[0] + b0B[0]);
      float fB = sigm  (a0B[1] + xv * wihB[1] + b0B[1]);
      float gB = tanh_f(a0B[2] + xv * wihB[2] + b0B[2]);
      float oB = sigm  (a0B[3] + xv * wihB[3] + b0B[3]);
      c0B = fB * c0B + iB * gB;
      pk0 = (unsigned)(unsigned short)f2bf(oA * tanh_f(c0A))
          | ((unsigned)(unsigned short)f2bf(oB * tanh_f(c0B)) << 16);
    }
    if (s >= 1) {
      float iA = sigm  (a1A[0] + b1A[0]);
      float fA = sigm  (a1A[1] + b1A[1]);
      float gA = tanh_f(a1A[2] + b1A[2]);
      float oA = sigm  (a1A[3] + b1A[3]);
      c1A = fA * c1A + iA * gA;
      float iB = sigm  (a1B[0] + b1B[0]);
      float fB = sigm  (a1B[1] + b1B[1]);
      float gB = tanh_f(a1B[2] + b1B[2]);
      float oB = sigm  (a1B[3] + b1B[3]);
      c1B = fB * c1B + iB * gB;
      pk1 = (unsigned)(unsigned short)f2bf(oA * tanh_f(c1A))
          | ((unsigned)(unsigned short)f2bf(oB * tanh_f(c1B)) << 16);
    }

    // ---- E: ONE combined coalesced store (unconditional) ----
    // pk1=0 at s=0 is the true h1[-1]=0; pk0=0 at s=Tz is never read.
    {
      size_t base = (size_t)(sl * 4 + w) * 2048 + (size_t)(gbase + l15) * 4 + q;
      llc_store64(hg + (size_t)(s & 1) * 65536 + base,
                  (u64)pk0 | ((u64)pk1 << 32));
    }

    // ---- F: drain (per-wave vmcnt(0) inside __syncthreads) + publish ----
    __syncthreads();
    if (tid == 0)
      llc_store32(myflag, (unsigned)(s + 1));
  }

  // ---- final head (sl==0 blocks): out = h1[Tz-1] @ w_lin^T + b_lin ----
  // h1[Tz-1] = hi32 halves of combined words written at iter Tz, parity 0.
  if (sl == 0) {
    {
      const unsigned expd = (unsigned)(Tz + 1);
      unsigned f = llc_load32(myflags);
      while (__ballot(f >= expd) != ~0ull) {
        __builtin_amdgcn_s_sleep(1);
        f = llc_load32(myflags);
      }
    }
    const u64* sp = hg + (size_t)(Tz & 1) * 65536;   // parity 0
    for (int k = 0; k < 4; ++k) {
      int i = tid + k * 256;
      int c = i & 1, b = (i >> 1) & 15, slw = i >> 5;
      size_t gi = ((size_t)slw * Bz + gbase + b) * 4 + 2 * c;
      u64 lo = llc_load64(sp + gi);
      u64 hi = llc_load64(sp + gi + 1);
      *(u64*)(h0s + b * KP + slw * 8 + c * 4) = (lo >> 32) | ((hi >> 32) << 32);
    }
    __syncthreads();
    for (int i = tid; i < BT * Pz; i += 256) {
      int b = i / Pz, p = i - b * Pz;
      const float* wr = wls + p * Hz;
      float acc = b_lin[p];
      for (int kk = 0; kk < Hz; ++kk)
        acc += bf2f(h0s[b * KP + kk]) * wr[kk];   // both in kpos order
      out[(gbase + b) * Pz + p] = acc;
    }
  }
}

extern "C" void kernel_launch(void* const* d_in, const int* in_sizes, int n_in,
                              void* d_out, int out_size, void* d_ws, size_t ws_size,
                              hipStream_t stream) {
  const float* x     = (const float*)d_in[0];
  const float* w_ih0 = (const float*)d_in[1];
  const float* w_hh0 = (const float*)d_in[2];
  const float* b_ih0 = (const float*)d_in[3];
  const float* b_hh0 = (const float*)d_in[4];
  const float* w_ih1 = (const float*)d_in[5];
  const float* w_hh1 = (const float*)d_in[6];
  const float* b_ih1 = (const float*)d_in[7];
  const float* b_hh1 = (const float*)d_in[8];
  const float* w_lin = (const float*)d_in[9];
  const float* b_lin = (const float*)d_in[10];
  float* out = (float*)d_out;

  unsigned char* ws = (unsigned char*)d_ws;
  u64* hg         = (u64*)ws;                          // [2][65536] u64 (512 KB/parity)
  unsigned* flags = (unsigned*)(ws + (1 << 20));       // [32 groups][32] u32 (8 used)
  // memset(0): h data zeros (bf16 0x0000 = initial hidden state) + flags = 0
  hipMemsetAsync(d_ws, 0, (1 << 20) + 4096, stream);

  size_t lds_bytes = (size_t)(2 * BT) * KP * 2     // h staging
                   + (size_t)(BT * XS) * 4         // x preload
                   + (size_t)(Pz * Hz) * 4;        // permuted w_lin (head)
  hipFuncSetAttribute((const void*)lstm2,
                      hipFuncAttributeMaxDynamicSharedMemorySize, (int)lds_bytes);
  lstm2<<<GB * GS, 256, lds_bytes, stream>>>(x, w_ih0, w_hh0, b_ih0, b_hh0,
                                             w_ih1, w_hh1, b_ih1, b_hh1,
                                             w_lin, b_lin, out, hg, flags);
}